// Round 6
// baseline (686.226 us; speedup 1.0000x reference)
//
// Re-bench of round-5 kernel (two acquisition timeouts in a row; no counters yet
// for: bf16 P/Q staging, 8-stream online-softmax agg). No code changes this round
// to preserve fault isolation on the stacked edits.
#include <hip/hip_runtime.h>
#include <math.h>

#define NEG_SLOPE 0.2f
#define NSTREAM 8

typedef short bf16x8 __attribute__((ext_vector_type(8)));
typedef float f32x4 __attribute__((ext_vector_type(4)));

__device__ __forceinline__ unsigned short f32_to_bf16_rne(float x) {
  unsigned int u = __float_as_uint(x);
  unsigned int r = u + 0x7FFFu + ((u >> 16) & 1u);
  return (unsigned short)(r >> 16);
}
__device__ __forceinline__ float bf16_bits_to_f32(unsigned short h) {
  return __uint_as_float((unsigned int)h << 16);
}

// ---------------- CSR build ----------------
__global__ void hist_kernel(const int* __restrict__ dst, int* __restrict__ cnt, int E) {
  int i = blockIdx.x * blockDim.x + threadIdx.x;
  if (i < E) atomicAdd(&cnt[dst[i]], 1);
}

__global__ __launch_bounds__(1024) void scan_block_kernel(const int* __restrict__ cnt,
                                                          int* __restrict__ row_start,
                                                          int* __restrict__ blk, int n) {
  __shared__ int buf[1024];
  int i = blockIdx.x * 1024 + threadIdx.x;
  int v = (i < n) ? cnt[i] : 0;
  buf[threadIdx.x] = v;
  __syncthreads();
  for (int off = 1; off < 1024; off <<= 1) {
    int t = (threadIdx.x >= (unsigned)off) ? buf[threadIdx.x - off] : 0;
    __syncthreads();
    buf[threadIdx.x] += t;
    __syncthreads();
  }
  if (i < n) row_start[i] = buf[threadIdx.x] - v;  // exclusive within block
  if (threadIdx.x == 1023) blk[blockIdx.x] = buf[1023];
}

__global__ __launch_bounds__(1024) void scan_tops_kernel(int* __restrict__ blk, int nb) {
  __shared__ int buf[1024];
  int v = (threadIdx.x < (unsigned)nb) ? blk[threadIdx.x] : 0;
  buf[threadIdx.x] = v;
  __syncthreads();
  for (int off = 1; off < 1024; off <<= 1) {
    int t = (threadIdx.x >= (unsigned)off) ? buf[threadIdx.x - off] : 0;
    __syncthreads();
    buf[threadIdx.x] += t;
    __syncthreads();
  }
  if (threadIdx.x < (unsigned)nb) blk[threadIdx.x] = buf[threadIdx.x] - v;  // exclusive
}

__global__ void scan_fixup_kernel(int* __restrict__ row_start, int* __restrict__ cursor,
                                  const int* __restrict__ blk, int n, int total) {
  int i = blockIdx.x * blockDim.x + threadIdx.x;
  if (i < n) {
    int r = row_start[i] + blk[i >> 10];
    row_start[i] = r;
    cursor[i] = r;
  }
  if (i == 0) row_start[n] = total;
}

__global__ void scatter_kernel(const int* __restrict__ dst, const int* __restrict__ src,
                               int* __restrict__ cursor, int* __restrict__ src_sorted, int E) {
  int i = blockIdx.x * blockDim.x + threadIdx.x;
  if (i < E) {
    int p = atomicAdd(&cursor[dst[i]], 1);
    src_sorted[p] = src[i];
  }
}

// ---------------- weight fragment pre-pack (hi/lo bf16, MFMA B-operand order) ----------------
// B-frag layout for mfma_f32_16x16x32_bf16: lane l holds col = l&15, k = (l>>4)*8 + j.
// Buffer layout: [mat(4)][ks(4)][nb(8)][lane(64)][j(8)]  (16B per lane -> coalesced frag loads)
__global__ void wfrag_kernel(const float* __restrict__ W0, const float* __restrict__ W1,
                             const float* __restrict__ W2, const float* __restrict__ W3,
                             unsigned short* __restrict__ hi, unsigned short* __restrict__ lo) {
  int t = blockIdx.x * 256 + threadIdx.x;  // 4 * 2048
  if (t >= 4 * 2048) return;
  int mat = t >> 11;
  int u = t & 2047;
  int l = u & 63, nb = (u >> 6) & 7, ks = u >> 9;
  const float* W = mat == 0 ? W0 : mat == 1 ? W1 : mat == 2 ? W2 : W3;
  int col = nb * 16 + (l & 15);
  int k0 = ks * 32 + ((l >> 4) << 3);
  unsigned short hv[8], lv[8];
#pragma unroll
  for (int j = 0; j < 8; j++) {
    float x = W[(size_t)(k0 + j) * 128 + col];
    unsigned short h = f32_to_bf16_rne(x);
    hv[j] = h;
    lv[j] = f32_to_bf16_rne(x - bf16_bits_to_f32(h));
  }
  size_t o = (size_t)t * 8;
#pragma unroll
  for (int j = 0; j < 8; j++) { hi[o + j] = hv[j]; lo[o + j] = lv[j]; }
}

// ---------------- dual GEMM via 3xBF16 MFMA ----------------
// P[M,128] = A@Ws + bs ; Q[M,128] = A@Wd + bd.  A fp32, split to hi/lo bf16 in-register.
// Outputs stored as bf16 (RNE after fp32 bias add).
// Block: 256 thr = 4 waves; wave w owns rows blockIdx.x*64 + w*16 .. +15; full N=128.
__global__ __launch_bounds__(256) void gemm_mfma_dual(
    const float* __restrict__ A,
    const unsigned short* __restrict__ FSh, const unsigned short* __restrict__ FSl,
    const unsigned short* __restrict__ FDh, const unsigned short* __restrict__ FDl,
    const float* __restrict__ bs_, const float* __restrict__ bd_,
    unsigned short* __restrict__ P, unsigned short* __restrict__ Q, int M) {
  const int tid = (int)threadIdx.x;
  const int w = tid >> 6;
  const int l = tid & 63;
  const int r0 = blockIdx.x * 64 + w * 16;
  const int arow = r0 + (l & 15);          // A-frag: row = lane&15
  const int koff = (l >> 4) << 3;          // A/B-frag: k = (lane>>4)*8 + j
  f32x4 accP[8] = {{0.f, 0.f, 0.f, 0.f}};
  f32x4 accQ[8] = {{0.f, 0.f, 0.f, 0.f}};
#pragma unroll
  for (int nb = 1; nb < 8; nb++) { accP[nb] = accP[0]; accQ[nb] = accQ[0]; }
  const bf16x8* fsh = (const bf16x8*)FSh;
  const bf16x8* fsl = (const bf16x8*)FSl;
  const bf16x8* fdh = (const bf16x8*)FDh;
  const bf16x8* fdl = (const bf16x8*)FDl;
#pragma unroll
  for (int ks = 0; ks < 4; ks++) {
    bf16x8 ahi, alo;
    if (arow < M) {
      const float* ap = A + (size_t)arow * 128 + ks * 32 + koff;
      float4 v0 = *(const float4*)ap;
      float4 v1 = *(const float4*)(ap + 4);
      float va[8] = {v0.x, v0.y, v0.z, v0.w, v1.x, v1.y, v1.z, v1.w};
#pragma unroll
      for (int j = 0; j < 8; j++) {
        unsigned short h = f32_to_bf16_rne(va[j]);
        ahi[j] = (short)h;
        alo[j] = (short)f32_to_bf16_rne(va[j] - bf16_bits_to_f32(h));
      }
    } else {
#pragma unroll
      for (int j = 0; j < 8; j++) { ahi[j] = 0; alo[j] = 0; }
    }
#pragma unroll
    for (int nb = 0; nb < 8; nb++) {
      int fi = (ks * 8 + nb) * 64 + l;
      bf16x8 bsh = fsh[fi];
      bf16x8 bsl = fsl[fi];
      bf16x8 bdh = fdh[fi];
      bf16x8 bdl = fdl[fi];
      accP[nb] = __builtin_amdgcn_mfma_f32_16x16x32_bf16(ahi, bsh, accP[nb], 0, 0, 0);
      accP[nb] = __builtin_amdgcn_mfma_f32_16x16x32_bf16(alo, bsh, accP[nb], 0, 0, 0);
      accP[nb] = __builtin_amdgcn_mfma_f32_16x16x32_bf16(ahi, bsl, accP[nb], 0, 0, 0);
      accQ[nb] = __builtin_amdgcn_mfma_f32_16x16x32_bf16(ahi, bdh, accQ[nb], 0, 0, 0);
      accQ[nb] = __builtin_amdgcn_mfma_f32_16x16x32_bf16(alo, bdh, accQ[nb], 0, 0, 0);
      accQ[nb] = __builtin_amdgcn_mfma_f32_16x16x32_bf16(ahi, bdl, accQ[nb], 0, 0, 0);
    }
  }
  // D-frag: col = lane&15, row = (lane>>4)*4 + reg   [m89-verified mapping]
  const int rbase = r0 + ((l >> 4) << 2);
  const int cl = l & 15;
#pragma unroll
  for (int nb = 0; nb < 8; nb++) {
    int col = nb * 16 + cl;
    float bP = bs_[col], bQ = bd_[col];
#pragma unroll
    for (int r = 0; r < 4; r++) {
      int grow = rbase + r;
      if (grow < M) {
        P[(size_t)grow * 128 + col] = f32_to_bf16_rne(accP[nb][r] + bP);
        Q[(size_t)grow * 128 + col] = f32_to_bf16_rne(accQ[nb][r] + bQ);
      }
    }
  }
}

// ---------------- GATv2 aggregation ----------------
// One wave per dst node; lane l owns dims (2l, 2l+1); head = l>>4.
// NSTREAM independent online-softmax streams (edges s0+s, s0+s+NSTREAM, ...) merged
// exactly at the end: NSTREAM-deep memory-level parallelism + short dependent chains.
__global__ __launch_bounds__(256) void gat_agg_kernel(
    const unsigned short* __restrict__ P,  // fs bf16 [N,128]
    const unsigned short* __restrict__ Q,  // fd bf16 [N,128]
    const float* __restrict__ attn,        // [128] = [H=4][D=32]
    const int* __restrict__ row_start,
    const int* __restrict__ src_sorted,
    float* __restrict__ out, int N, int do_relu) {
  int wave = (int)((blockIdx.x * blockDim.x + threadIdx.x) >> 6);
  int lane = (int)(threadIdx.x & 63);
  if (wave >= N) return;
  const int off = lane * 2;
  ushort2 qb = *(const ushort2*)&Q[(size_t)wave * 128 + off];
  const float fd0 = bf16_bits_to_f32(qb.x), fd1 = bf16_bits_to_f32(qb.y);
  const float2 av = *(const float2*)&attn[off];
  const int s0 = row_start[wave], s1 = row_start[wave + 1];

  float m[NSTREAM], den[NSTREAM], a0[NSTREAM], a1[NSTREAM], c0[NSTREAM], c1[NSTREAM];
#pragma unroll
  for (int s = 0; s < NSTREAM; s++) {
    m[s] = -INFINITY; den[s] = 0.f; a0[s] = 0.f; a1[s] = 0.f; c0[s] = 0.f; c1[s] = 0.f;
  }
  // prologue: load first edge of each stream
#pragma unroll
  for (int s = 0; s < NSTREAM; s++) {
    if (s0 + s < s1) {
      int sv = src_sorted[s0 + s];
      ushort2 pb = *(const ushort2*)&P[(size_t)sv * 128 + off];
      c0[s] = bf16_bits_to_f32(pb.x); c1[s] = bf16_bits_to_f32(pb.y);
    }
  }
  for (int base = s0; base < s1; base += NSTREAM) {
    float n0[NSTREAM], n1[NSTREAM];
    // issue next NSTREAM gathers (conditions wave-uniform)
#pragma unroll
    for (int s = 0; s < NSTREAM; s++) {
      int nx = base + NSTREAM + s;
      if (nx < s1) {
        int sv = src_sorted[nx];
        ushort2 pb = *(const ushort2*)&P[(size_t)sv * 128 + off];
        n0[s] = bf16_bits_to_f32(pb.x); n1[s] = bf16_bits_to_f32(pb.y);
      } else { n0[s] = 0.f; n1[s] = 0.f; }
    }
    // NSTREAM independent compute chains
#pragma unroll
    for (int s = 0; s < NSTREAM; s++) {
      if (base + s < s1) {
        float x0 = c0[s] + fd0, x1 = c1[s] + fd1;
        x0 = x0 > 0.f ? x0 : NEG_SLOPE * x0;
        x1 = x1 > 0.f ? x1 : NEG_SLOPE * x1;
        float t = x0 * av.x + x1 * av.y;      // per-head dot over the head's 16 lanes
        t += __shfl_xor(t, 1, 16);
        t += __shfl_xor(t, 2, 16);
        t += __shfl_xor(t, 4, 16);
        t += __shfl_xor(t, 8, 16);
        float mn = fmaxf(m[s], t);            // branchless online softmax
        float sc = __expf(m[s] - mn);
        float ex = __expf(t - mn);
        den[s] = den[s] * sc + ex;
        a0[s] = a0[s] * sc + ex * c0[s];
        a1[s] = a1[s] * sc + ex * c1[s];
        m[s] = mn;
      }
    }
#pragma unroll
    for (int s = 0; s < NSTREAM; s++) { c0[s] = n0[s]; c1[s] = n1[s]; }
  }
  // merge the NSTREAM streams (exact flash-style merge; empty streams contribute 0)
  float M2 = m[0];
#pragma unroll
  for (int s = 1; s < NSTREAM; s++) M2 = fmaxf(M2, m[s]);
  float D = 0.f, A0 = 0.f, A1 = 0.f;
#pragma unroll
  for (int s = 0; s < NSTREAM; s++) {
    float sc = __expf(m[s] - M2);             // exp(-inf)=0 for empty streams
    D += den[s] * sc;
    A0 += a0[s] * sc;
    A1 += a1[s] * sc;
  }
  float2 o;
  if (s1 > s0) { o.x = A0 / D; o.y = A1 / D; }
  else         { o.x = 0.f; o.y = 0.f; }
  if (do_relu) { o.x = fmaxf(o.x, 0.f); o.y = fmaxf(o.y, 0.f); }
  *(float2*)&out[(size_t)wave * 128 + off] = o;
}

// ---------------- link-prediction scores: one wave per query ----------------
__global__ __launch_bounds__(256) void edge_score_kernel(
    const float* __restrict__ H, const int* __restrict__ qs, const int* __restrict__ qd,
    float* __restrict__ out, int NQ) {
  int wave = (int)((blockIdx.x * blockDim.x + threadIdx.x) >> 6);
  int lane = (int)(threadIdx.x & 63);
  if (wave >= NQ) return;
  int a = qs[wave], b = qd[wave];
  float2 x = *(const float2*)&H[(size_t)a * 128 + lane * 2];
  float2 y = *(const float2*)&H[(size_t)b * 128 + lane * 2];
  float t = x.x * y.x + x.y * y.y;
#pragma unroll
  for (int mask = 1; mask < 64; mask <<= 1) t += __shfl_xor(t, mask, 64);
  if (lane == 0) out[wave] = 1.f / (1.f + __expf(-t));
}

// ---------------- launch ----------------
extern "C" void kernel_launch(void* const* d_in, const int* in_sizes, int n_in,
                              void* d_out, int out_size, void* d_ws, size_t ws_size,
                              hipStream_t stream) {
  const float* feat  = (const float*)d_in[0];
  const int*   esrc  = (const int*)d_in[1];
  const int*   edst  = (const int*)d_in[2];
  const int*   qsrc  = (const int*)d_in[3];
  const int*   qdst  = (const int*)d_in[4];
  const float* W1s   = (const float*)d_in[5];
  const float* b1s   = (const float*)d_in[6];
  const float* W1d   = (const float*)d_in[7];
  const float* b1d   = (const float*)d_in[8];
  const float* attn1 = (const float*)d_in[9];
  const float* W2s   = (const float*)d_in[10];
  const float* b2s   = (const float*)d_in[11];
  const float* W2d   = (const float*)d_in[12];
  const float* b2d   = (const float*)d_in[13];
  const float* attn2 = (const float*)d_in[14];
  float* out = (float*)d_out;

  const int N  = in_sizes[0] / 128;
  const int E  = in_sizes[1];
  const int NQ = in_sizes[3];

  char* p = (char*)d_ws;
  auto alloc = [&](size_t bytes) -> char* {
    char* r = p;
    p += (bytes + 255) & ~(size_t)255;
    return r;
  };
  unsigned short* P = (unsigned short*)alloc((size_t)N * 128 * 2);  // bf16
  unsigned short* Q = (unsigned short*)alloc((size_t)N * 128 * 2);  // bf16
  float* H          = (float*)alloc((size_t)N * 128 * 4);
  int*   cnt        = (int*)alloc((size_t)N * 4);
  int*   row_start  = (int*)alloc((size_t)(N + 1) * 4);
  int*   cursor     = (int*)alloc((size_t)N * 4);
  int*   src_sorted = (int*)alloc((size_t)E * 4);
  int*   blk        = (int*)alloc(1024 * 4);
  unsigned short* FBhi = (unsigned short*)alloc(4 * 2048 * 8 * 2);  // 128KB
  unsigned short* FBlo = (unsigned short*)alloc(4 * 2048 * 8 * 2);

  // weight fragment pre-pack (independent of graph build)
  wfrag_kernel<<<32, 256, 0, stream>>>(W1s, W1d, W2s, W2d, FBhi, FBlo);

  // CSR build (edges grouped by dst; order within a node is arbitrary — sums only)
  const int nb = (N + 1023) / 1024;
  hipMemsetAsync(cnt, 0, (size_t)N * 4, stream);
  hist_kernel<<<(E + 255) / 256, 256, 0, stream>>>(edst, cnt, E);
  scan_block_kernel<<<nb, 1024, 0, stream>>>(cnt, row_start, blk, N);
  scan_tops_kernel<<<1, 1024, 0, stream>>>(blk, nb);
  scan_fixup_kernel<<<(N + 255) / 256, 256, 0, stream>>>(row_start, cursor, blk, N, E);
  scatter_kernel<<<(E + 255) / 256, 256, 0, stream>>>(edst, esrc, cursor, src_sorted, E);

  const int gblocks = (N + 63) / 64;
  const int per_mat = 2048 * 8;  // ushorts per matrix in FB buffers

  // layer 1
  gemm_mfma_dual<<<gblocks, 256, 0, stream>>>(
      feat, FBhi + 0 * per_mat, FBlo + 0 * per_mat, FBhi + 1 * per_mat, FBlo + 1 * per_mat,
      b1s, b1d, P, Q, N);
  gat_agg_kernel<<<(N + 3) / 4, 256, 0, stream>>>(P, Q, attn1, row_start, src_sorted, H, N, 1);

  // layer 2
  gemm_mfma_dual<<<gblocks, 256, 0, stream>>>(
      H, FBhi + 2 * per_mat, FBlo + 2 * per_mat, FBhi + 3 * per_mat, FBlo + 3 * per_mat,
      b2s, b2d, P, Q, N);
  gat_agg_kernel<<<(N + 3) / 4, 256, 0, stream>>>(P, Q, attn2, row_start, src_sorted, H, N, 0);

  // scores
  edge_score_kernel<<<(NQ + 3) / 4, 256, 0, stream>>>(H, qsrc, qdst, out, NQ);
}

// Round 7
// 467.512 us; speedup vs baseline: 1.4678x; 1.4678x over previous
//
#include <hip/hip_runtime.h>
#include <math.h>

#define NEG_SLOPE 0.2f
#define NSTREAM 8
#define IDX_SENT 0x7FFFFFFF

typedef short bf16x8 __attribute__((ext_vector_type(8)));
typedef float f32x4 __attribute__((ext_vector_type(4)));

__device__ __forceinline__ unsigned short f32_to_bf16_rne(float x) {
  unsigned int u = __float_as_uint(x);
  unsigned int r = u + 0x7FFFu + ((u >> 16) & 1u);
  return (unsigned short)(r >> 16);
}
__device__ __forceinline__ float bf16_bits_to_f32(unsigned short h) {
  return __uint_as_float((unsigned int)h << 16);
}

// ---------------- CSR build ----------------
__global__ void hist_kernel(const int* __restrict__ dst, int* __restrict__ cnt, int E) {
  int i = blockIdx.x * blockDim.x + threadIdx.x;
  if (i < E) atomicAdd(&cnt[dst[i]], 1);
}

__global__ __launch_bounds__(1024) void scan_block_kernel(const int* __restrict__ cnt,
                                                          int* __restrict__ row_start,
                                                          int* __restrict__ blk, int n) {
  __shared__ int buf[1024];
  int i = blockIdx.x * 1024 + threadIdx.x;
  int v = (i < n) ? cnt[i] : 0;
  buf[threadIdx.x] = v;
  __syncthreads();
  for (int off = 1; off < 1024; off <<= 1) {
    int t = (threadIdx.x >= (unsigned)off) ? buf[threadIdx.x - off] : 0;
    __syncthreads();
    buf[threadIdx.x] += t;
    __syncthreads();
  }
  if (i < n) row_start[i] = buf[threadIdx.x] - v;  // exclusive within block
  if (threadIdx.x == 1023) blk[blockIdx.x] = buf[1023];
}

__global__ __launch_bounds__(1024) void scan_tops_kernel(int* __restrict__ blk, int nb) {
  __shared__ int buf[1024];
  int v = (threadIdx.x < (unsigned)nb) ? blk[threadIdx.x] : 0;
  buf[threadIdx.x] = v;
  __syncthreads();
  for (int off = 1; off < 1024; off <<= 1) {
    int t = (threadIdx.x >= (unsigned)off) ? buf[threadIdx.x - off] : 0;
    __syncthreads();
    buf[threadIdx.x] += t;
    __syncthreads();
  }
  if (threadIdx.x < (unsigned)nb) blk[threadIdx.x] = buf[threadIdx.x] - v;  // exclusive
}

__global__ void scan_fixup_kernel(int* __restrict__ row_start, int* __restrict__ cursor,
                                  const int* __restrict__ blk, int n, int total) {
  int i = blockIdx.x * blockDim.x + threadIdx.x;
  if (i < n) {
    int r = row_start[i] + blk[i >> 10];
    row_start[i] = r;
    cursor[i] = r;
  }
  if (i == 0) row_start[n] = total;
}

__global__ void scatter_kernel(const int* __restrict__ dst, const int* __restrict__ src,
                               int* __restrict__ cursor, int* __restrict__ src_sorted, int E) {
  int i = blockIdx.x * blockDim.x + threadIdx.x;
  if (i < E) {
    int p = atomicAdd(&cursor[dst[i]], 1);
    src_sorted[p] = src[i];
  }
}

// ---------------- weight fragment pre-pack (hi/lo bf16, MFMA B-operand order) ----------------
// B-frag layout for mfma_f32_16x16x32_bf16: lane l holds col = l&15, k = (l>>4)*8 + j.
// Buffer layout: [mat(4)][ks(4)][nb(8)][lane(64)][j(8)]  (16B per lane -> coalesced frag loads)
__global__ void wfrag_kernel(const float* __restrict__ W0, const float* __restrict__ W1,
                             const float* __restrict__ W2, const float* __restrict__ W3,
                             unsigned short* __restrict__ hi, unsigned short* __restrict__ lo) {
  int t = blockIdx.x * 256 + threadIdx.x;  // 4 * 2048
  if (t >= 4 * 2048) return;
  int mat = t >> 11;
  int u = t & 2047;
  int l = u & 63, nb = (u >> 6) & 7, ks = u >> 9;
  const float* W = mat == 0 ? W0 : mat == 1 ? W1 : mat == 2 ? W2 : W3;
  int col = nb * 16 + (l & 15);
  int k0 = ks * 32 + ((l >> 4) << 3);
  unsigned short hv[8], lv[8];
#pragma unroll
  for (int j = 0; j < 8; j++) {
    float x = W[(size_t)(k0 + j) * 128 + col];
    unsigned short h = f32_to_bf16_rne(x);
    hv[j] = h;
    lv[j] = f32_to_bf16_rne(x - bf16_bits_to_f32(h));
  }
  size_t o = (size_t)t * 8;
#pragma unroll
  for (int j = 0; j < 8; j++) { hi[o + j] = hv[j]; lo[o + j] = lv[j]; }
}

// ---------------- dual GEMM via 3xBF16 MFMA ----------------
// P[M,128] = A@Ws + bs ; Q[M,128] = A@Wd + bd.  A fp32, split to hi/lo bf16 in-register.
// Outputs stored as bf16 (RNE after fp32 bias add).
__global__ __launch_bounds__(256) void gemm_mfma_dual(
    const float* __restrict__ A,
    const unsigned short* __restrict__ FSh, const unsigned short* __restrict__ FSl,
    const unsigned short* __restrict__ FDh, const unsigned short* __restrict__ FDl,
    const float* __restrict__ bs_, const float* __restrict__ bd_,
    unsigned short* __restrict__ P, unsigned short* __restrict__ Q, int M) {
  const int tid = (int)threadIdx.x;
  const int w = tid >> 6;
  const int l = tid & 63;
  const int r0 = blockIdx.x * 64 + w * 16;
  const int arow = r0 + (l & 15);          // A-frag: row = lane&15
  const int koff = (l >> 4) << 3;          // A/B-frag: k = (lane>>4)*8 + j
  f32x4 accP[8] = {{0.f, 0.f, 0.f, 0.f}};
  f32x4 accQ[8] = {{0.f, 0.f, 0.f, 0.f}};
#pragma unroll
  for (int nb = 1; nb < 8; nb++) { accP[nb] = accP[0]; accQ[nb] = accQ[0]; }
  const bf16x8* fsh = (const bf16x8*)FSh;
  const bf16x8* fsl = (const bf16x8*)FSl;
  const bf16x8* fdh = (const bf16x8*)FDh;
  const bf16x8* fdl = (const bf16x8*)FDl;
#pragma unroll
  for (int ks = 0; ks < 4; ks++) {
    bf16x8 ahi, alo;
    if (arow < M) {
      const float* ap = A + (size_t)arow * 128 + ks * 32 + koff;
      float4 v0 = *(const float4*)ap;
      float4 v1 = *(const float4*)(ap + 4);
      float va[8] = {v0.x, v0.y, v0.z, v0.w, v1.x, v1.y, v1.z, v1.w};
#pragma unroll
      for (int j = 0; j < 8; j++) {
        unsigned short h = f32_to_bf16_rne(va[j]);
        ahi[j] = (short)h;
        alo[j] = (short)f32_to_bf16_rne(va[j] - bf16_bits_to_f32(h));
      }
    } else {
#pragma unroll
      for (int j = 0; j < 8; j++) { ahi[j] = 0; alo[j] = 0; }
    }
#pragma unroll
    for (int nb = 0; nb < 8; nb++) {
      int fi = (ks * 8 + nb) * 64 + l;
      bf16x8 bsh = fsh[fi];
      bf16x8 bsl = fsl[fi];
      bf16x8 bdh = fdh[fi];
      bf16x8 bdl = fdl[fi];
      accP[nb] = __builtin_amdgcn_mfma_f32_16x16x32_bf16(ahi, bsh, accP[nb], 0, 0, 0);
      accP[nb] = __builtin_amdgcn_mfma_f32_16x16x32_bf16(alo, bsh, accP[nb], 0, 0, 0);
      accP[nb] = __builtin_amdgcn_mfma_f32_16x16x32_bf16(ahi, bsl, accP[nb], 0, 0, 0);
      accQ[nb] = __builtin_amdgcn_mfma_f32_16x16x32_bf16(ahi, bdh, accQ[nb], 0, 0, 0);
      accQ[nb] = __builtin_amdgcn_mfma_f32_16x16x32_bf16(alo, bdh, accQ[nb], 0, 0, 0);
      accQ[nb] = __builtin_amdgcn_mfma_f32_16x16x32_bf16(ahi, bdl, accQ[nb], 0, 0, 0);
    }
  }
  // D-frag: col = lane&15, row = (lane>>4)*4 + reg   [m89-verified mapping]
  const int rbase = r0 + ((l >> 4) << 2);
  const int cl = l & 15;
#pragma unroll
  for (int nb = 0; nb < 8; nb++) {
    int col = nb * 16 + cl;
    float bP = bs_[col], bQ = bd_[col];
#pragma unroll
    for (int r = 0; r < 4; r++) {
      int grow = rbase + r;
      if (grow < M) {
        P[(size_t)grow * 128 + col] = f32_to_bf16_rne(accP[nb][r] + bP);
        Q[(size_t)grow * 128 + col] = f32_to_bf16_rne(accQ[nb][r] + bQ);
      }
    }
  }
}

// ---------------- GATv2 aggregation ----------------
// One wave per dst node; lane l owns dims (2l, 2l+1); head = l>>4.
// 3-stage software pipeline, NSTREAM-wide chunks:
//   loop top: retire gathers of chunk c (cur <- nxt), issue gathers of chunk c+1
//   (indices already resolved), issue index loads for chunk c+2, compute chunk c.
// Rows kept as raw uint (ushort2 of bf16): 1 VGPR each; decode by bit-ops at use.
// __launch_bounds__(256,4): VGPR cap 128 so the pipeline state stays in registers
// (round-6 lesson: default bounds gave 52 VGPR and the compiler serialized all MLP).
__global__ __launch_bounds__(256, 4) void gat_agg_kernel(
    const unsigned short* __restrict__ P,  // fs bf16 [N,128]
    const unsigned short* __restrict__ Q,  // fd bf16 [N,128]
    const float* __restrict__ attn,        // [128] = [H=4][D=32]
    const int* __restrict__ row_start,
    const int* __restrict__ src_sorted,
    float* __restrict__ out, int N, int do_relu) {
  int wave = (int)((blockIdx.x * blockDim.x + threadIdx.x) >> 6);
  int lane = (int)(threadIdx.x & 63);
  if (wave >= N) return;
  const int off = lane * 2;
  ushort2 qb = *(const ushort2*)&Q[(size_t)wave * 128 + off];
  const float fd0 = bf16_bits_to_f32(qb.x), fd1 = bf16_bits_to_f32(qb.y);
  const float2 av = *(const float2*)&attn[off];
  const int s0 = row_start[wave], s1 = row_start[wave + 1];

  float m[NSTREAM], den[NSTREAM], a0[NSTREAM], a1[NSTREAM];
  unsigned int cur[NSTREAM], nxt[NSTREAM];
  int idxn[NSTREAM];
#pragma unroll
  for (int s = 0; s < NSTREAM; s++) {
    m[s] = -INFINITY; den[s] = 0.f; a0[s] = 0.f; a1[s] = 0.f;
    cur[s] = 0u; nxt[s] = 0u;
  }
  // prologue: indices of chunk 0, gathers of chunk 0, indices of chunk 1
#pragma unroll
  for (int s = 0; s < NSTREAM; s++)
    idxn[s] = (s0 + s < s1) ? src_sorted[s0 + s] : IDX_SENT;
#pragma unroll
  for (int s = 0; s < NSTREAM; s++)
    if (idxn[s] != IDX_SENT)
      nxt[s] = *(const unsigned int*)&P[(size_t)idxn[s] * 128 + off];
#pragma unroll
  for (int s = 0; s < NSTREAM; s++) {
    int nx = s0 + NSTREAM + s;
    idxn[s] = (nx < s1) ? src_sorted[nx] : IDX_SENT;
  }

#pragma unroll 1
  for (int base = s0; base < s1; base += NSTREAM) {
    // retire chunk c gathers (waitcnt lands here), free nxt for re-issue
#pragma unroll
    for (int s = 0; s < NSTREAM; s++) cur[s] = nxt[s];
    // issue gathers for chunk c+1 (indices already in registers)
#pragma unroll
    for (int s = 0; s < NSTREAM; s++)
      nxt[s] = (idxn[s] != IDX_SENT)
                   ? *(const unsigned int*)&P[(size_t)idxn[s] * 128 + off]
                   : 0u;
    // issue index loads for chunk c+2 (sequential, cache-friendly)
#pragma unroll
    for (int s = 0; s < NSTREAM; s++) {
      int nx = base + 2 * NSTREAM + s;
      idxn[s] = (nx < s1) ? src_sorted[nx] : IDX_SENT;
    }
    // compute chunk c
#pragma unroll
    for (int s = 0; s < NSTREAM; s++) {
      if (base + s < s1) {
        float c0 = __uint_as_float(cur[s] << 16);
        float c1 = __uint_as_float(cur[s] & 0xFFFF0000u);
        float x0 = c0 + fd0, x1 = c1 + fd1;
        x0 = x0 > 0.f ? x0 : NEG_SLOPE * x0;
        x1 = x1 > 0.f ? x1 : NEG_SLOPE * x1;
        float t = x0 * av.x + x1 * av.y;      // per-head dot over the head's 16 lanes
        t += __shfl_xor(t, 1, 16);
        t += __shfl_xor(t, 2, 16);
        t += __shfl_xor(t, 4, 16);
        t += __shfl_xor(t, 8, 16);
        float mn = fmaxf(m[s], t);            // branchless online softmax
        float sc = __expf(m[s] - mn);
        float ex = __expf(t - mn);
        den[s] = den[s] * sc + ex;
        a0[s] = a0[s] * sc + ex * c0;
        a1[s] = a1[s] * sc + ex * c1;
        m[s] = mn;
      }
    }
  }
  // merge the NSTREAM streams (exact flash-style merge; empty streams contribute 0)
  float M2 = m[0];
#pragma unroll
  for (int s = 1; s < NSTREAM; s++) M2 = fmaxf(M2, m[s]);
  float D = 0.f, A0 = 0.f, A1 = 0.f;
#pragma unroll
  for (int s = 0; s < NSTREAM; s++) {
    float sc = __expf(m[s] - M2);             // exp(-inf)=0 for empty streams
    D += den[s] * sc;
    A0 += a0[s] * sc;
    A1 += a1[s] * sc;
  }
  float2 o;
  if (s1 > s0) { o.x = A0 / D; o.y = A1 / D; }
  else         { o.x = 0.f; o.y = 0.f; }
  if (do_relu) { o.x = fmaxf(o.x, 0.f); o.y = fmaxf(o.y, 0.f); }
  *(float2*)&out[(size_t)wave * 128 + off] = o;
}

// ---------------- link-prediction scores: one wave per query ----------------
__global__ __launch_bounds__(256) void edge_score_kernel(
    const float* __restrict__ H, const int* __restrict__ qs, const int* __restrict__ qd,
    float* __restrict__ out, int NQ) {
  int wave = (int)((blockIdx.x * blockDim.x + threadIdx.x) >> 6);
  int lane = (int)(threadIdx.x & 63);
  if (wave >= NQ) return;
  int a = qs[wave], b = qd[wave];
  float2 x = *(const float2*)&H[(size_t)a * 128 + lane * 2];
  float2 y = *(const float2*)&H[(size_t)b * 128 + lane * 2];
  float t = x.x * y.x + x.y * y.y;
#pragma unroll
  for (int mask = 1; mask < 64; mask <<= 1) t += __shfl_xor(t, mask, 64);
  if (lane == 0) out[wave] = 1.f / (1.f + __expf(-t));
}

// ---------------- launch ----------------
extern "C" void kernel_launch(void* const* d_in, const int* in_sizes, int n_in,
                              void* d_out, int out_size, void* d_ws, size_t ws_size,
                              hipStream_t stream) {
  const float* feat  = (const float*)d_in[0];
  const int*   esrc  = (const int*)d_in[1];
  const int*   edst  = (const int*)d_in[2];
  const int*   qsrc  = (const int*)d_in[3];
  const int*   qdst  = (const int*)d_in[4];
  const float* W1s   = (const float*)d_in[5];
  const float* b1s   = (const float*)d_in[6];
  const float* W1d   = (const float*)d_in[7];
  const float* b1d   = (const float*)d_in[8];
  const float* attn1 = (const float*)d_in[9];
  const float* W2s   = (const float*)d_in[10];
  const float* b2s   = (const float*)d_in[11];
  const float* W2d   = (const float*)d_in[12];
  const float* b2d   = (const float*)d_in[13];
  const float* attn2 = (const float*)d_in[14];
  float* out = (float*)d_out;

  const int N  = in_sizes[0] / 128;
  const int E  = in_sizes[1];
  const int NQ = in_sizes[3];

  char* p = (char*)d_ws;
  auto alloc = [&](size_t bytes) -> char* {
    char* r = p;
    p += (bytes + 255) & ~(size_t)255;
    return r;
  };
  unsigned short* P = (unsigned short*)alloc((size_t)N * 128 * 2);  // bf16
  unsigned short* Q = (unsigned short*)alloc((size_t)N * 128 * 2);  // bf16
  float* H          = (float*)alloc((size_t)N * 128 * 4);
  int*   cnt        = (int*)alloc((size_t)N * 4);
  int*   row_start  = (int*)alloc((size_t)(N + 1) * 4);
  int*   cursor     = (int*)alloc((size_t)N * 4);
  int*   src_sorted = (int*)alloc((size_t)E * 4);
  int*   blk        = (int*)alloc(1024 * 4);
  unsigned short* FBhi = (unsigned short*)alloc(4 * 2048 * 8 * 2);  // 128KB
  unsigned short* FBlo = (unsigned short*)alloc(4 * 2048 * 8 * 2);

  // weight fragment pre-pack (independent of graph build)
  wfrag_kernel<<<32, 256, 0, stream>>>(W1s, W1d, W2s, W2d, FBhi, FBlo);

  // CSR build (edges grouped by dst; order within a node is arbitrary — sums only)
  const int nb = (N + 1023) / 1024;
  hipMemsetAsync(cnt, 0, (size_t)N * 4, stream);
  hist_kernel<<<(E + 255) / 256, 256, 0, stream>>>(edst, cnt, E);
  scan_block_kernel<<<nb, 1024, 0, stream>>>(cnt, row_start, blk, N);
  scan_tops_kernel<<<1, 1024, 0, stream>>>(blk, nb);
  scan_fixup_kernel<<<(N + 255) / 256, 256, 0, stream>>>(row_start, cursor, blk, N, E);
  scatter_kernel<<<(E + 255) / 256, 256, 0, stream>>>(edst, esrc, cursor, src_sorted, E);

  const int gblocks = (N + 63) / 64;
  const int per_mat = 2048 * 8;  // ushorts per matrix in FB buffers

  // layer 1
  gemm_mfma_dual<<<gblocks, 256, 0, stream>>>(
      feat, FBhi + 0 * per_mat, FBlo + 0 * per_mat, FBhi + 1 * per_mat, FBlo + 1 * per_mat,
      b1s, b1d, P, Q, N);
  gat_agg_kernel<<<(N + 3) / 4, 256, 0, stream>>>(P, Q, attn1, row_start, src_sorted, H, N, 1);

  // layer 2
  gemm_mfma_dual<<<gblocks, 256, 0, stream>>>(
      H, FBhi + 2 * per_mat, FBlo + 2 * per_mat, FBhi + 3 * per_mat, FBlo + 3 * per_mat,
      b2s, b2d, P, Q, N);
  gat_agg_kernel<<<(N + 3) / 4, 256, 0, stream>>>(P, Q, attn2, row_start, src_sorted, H, N, 0);

  // scores
  edge_score_kernel<<<(NQ + 3) / 4, 256, 0, stream>>>(H, qsrc, qdst, out, NQ);
}

// Round 10
// 358.630 us; speedup vs baseline: 1.9135x; 1.3036x over previous
//
// Re-bench of round-8 kernel (second consecutive acquisition timeout; the
// 4-edge/wave-step agg remap is still unvalidated). Byte-identical resubmission
// to preserve fault isolation.
#include <hip/hip_runtime.h>
#include <math.h>

#define NEG_SLOPE 0.2f

typedef short bf16x8 __attribute__((ext_vector_type(8)));
typedef float f32x4 __attribute__((ext_vector_type(4)));

__device__ __forceinline__ unsigned short f32_to_bf16_rne(float x) {
  unsigned int u = __float_as_uint(x);
  unsigned int r = u + 0x7FFFu + ((u >> 16) & 1u);
  return (unsigned short)(r >> 16);
}
__device__ __forceinline__ float bf16_bits_to_f32(unsigned short h) {
  return __uint_as_float((unsigned int)h << 16);
}
__device__ __forceinline__ void decode8(uint4 v, float* f) {
  f[0] = __uint_as_float(v.x << 16);
  f[1] = __uint_as_float(v.x & 0xFFFF0000u);
  f[2] = __uint_as_float(v.y << 16);
  f[3] = __uint_as_float(v.y & 0xFFFF0000u);
  f[4] = __uint_as_float(v.z << 16);
  f[5] = __uint_as_float(v.z & 0xFFFF0000u);
  f[6] = __uint_as_float(v.w << 16);
  f[7] = __uint_as_float(v.w & 0xFFFF0000u);
}

// ---------------- CSR build ----------------
__global__ void hist_kernel(const int* __restrict__ dst, int* __restrict__ cnt, int E) {
  int i = blockIdx.x * blockDim.x + threadIdx.x;
  if (i < E) atomicAdd(&cnt[dst[i]], 1);
}

__global__ __launch_bounds__(1024) void scan_block_kernel(const int* __restrict__ cnt,
                                                          int* __restrict__ row_start,
                                                          int* __restrict__ blk, int n) {
  __shared__ int buf[1024];
  int i = blockIdx.x * 1024 + threadIdx.x;
  int v = (i < n) ? cnt[i] : 0;
  buf[threadIdx.x] = v;
  __syncthreads();
  for (int off = 1; off < 1024; off <<= 1) {
    int t = (threadIdx.x >= (unsigned)off) ? buf[threadIdx.x - off] : 0;
    __syncthreads();
    buf[threadIdx.x] += t;
    __syncthreads();
  }
  if (i < n) row_start[i] = buf[threadIdx.x] - v;  // exclusive within block
  if (threadIdx.x == 1023) blk[blockIdx.x] = buf[1023];
}

__global__ __launch_bounds__(1024) void scan_tops_kernel(int* __restrict__ blk, int nb) {
  __shared__ int buf[1024];
  int v = (threadIdx.x < (unsigned)nb) ? blk[threadIdx.x] : 0;
  buf[threadIdx.x] = v;
  __syncthreads();
  for (int off = 1; off < 1024; off <<= 1) {
    int t = (threadIdx.x >= (unsigned)off) ? buf[threadIdx.x - off] : 0;
    __syncthreads();
    buf[threadIdx.x] += t;
    __syncthreads();
  }
  if (threadIdx.x < (unsigned)nb) blk[threadIdx.x] = buf[threadIdx.x] - v;  // exclusive
}

__global__ void scan_fixup_kernel(int* __restrict__ row_start, int* __restrict__ cursor,
                                  const int* __restrict__ blk, int n, int total) {
  int i = blockIdx.x * blockDim.x + threadIdx.x;
  if (i < n) {
    int r = row_start[i] + blk[i >> 10];
    row_start[i] = r;
    cursor[i] = r;
  }
  if (i == 0) row_start[n] = total;
}

__global__ void scatter_kernel(const int* __restrict__ dst, const int* __restrict__ src,
                               int* __restrict__ cursor, int* __restrict__ src_sorted, int E) {
  int i = blockIdx.x * blockDim.x + threadIdx.x;
  if (i < E) {
    int p = atomicAdd(&cursor[dst[i]], 1);
    src_sorted[p] = src[i];
  }
}

// ---------------- weight fragment pre-pack (hi/lo bf16, MFMA B-operand order) ----------------
// B-frag layout for mfma_f32_16x16x32_bf16: lane l holds col = l&15, k = (l>>4)*8 + j.
// Buffer layout: [mat(4)][ks(4)][nb(8)][lane(64)][j(8)]  (16B per lane -> coalesced frag loads)
__global__ void wfrag_kernel(const float* __restrict__ W0, const float* __restrict__ W1,
                             const float* __restrict__ W2, const float* __restrict__ W3,
                             unsigned short* __restrict__ hi, unsigned short* __restrict__ lo) {
  int t = blockIdx.x * 256 + threadIdx.x;  // 4 * 2048
  if (t >= 4 * 2048) return;
  int mat = t >> 11;
  int u = t & 2047;
  int l = u & 63, nb = (u >> 6) & 7, ks = u >> 9;
  const float* W = mat == 0 ? W0 : mat == 1 ? W1 : mat == 2 ? W2 : W3;
  int col = nb * 16 + (l & 15);
  int k0 = ks * 32 + ((l >> 4) << 3);
  unsigned short hv[8], lv[8];
#pragma unroll
  for (int j = 0; j < 8; j++) {
    float x = W[(size_t)(k0 + j) * 128 + col];
    unsigned short h = f32_to_bf16_rne(x);
    hv[j] = h;
    lv[j] = f32_to_bf16_rne(x - bf16_bits_to_f32(h));
  }
  size_t o = (size_t)t * 8;
#pragma unroll
  for (int j = 0; j < 8; j++) { hi[o + j] = hv[j]; lo[o + j] = lv[j]; }
}

// ---------------- dual GEMM via 3xBF16 MFMA ----------------
// P[M,128] = A@Ws + bs ; Q[M,128] = A@Wd + bd.  A fp32, split to hi/lo bf16 in-register.
// Outputs stored as bf16 (RNE after fp32 bias add).
__global__ __launch_bounds__(256) void gemm_mfma_dual(
    const float* __restrict__ A,
    const unsigned short* __restrict__ FSh, const unsigned short* __restrict__ FSl,
    const unsigned short* __restrict__ FDh, const unsigned short* __restrict__ FDl,
    const float* __restrict__ bs_, const float* __restrict__ bd_,
    unsigned short* __restrict__ P, unsigned short* __restrict__ Q, int M) {
  const int tid = (int)threadIdx.x;
  const int w = tid >> 6;
  const int l = tid & 63;
  const int r0 = blockIdx.x * 64 + w * 16;
  const int arow = r0 + (l & 15);          // A-frag: row = lane&15
  const int koff = (l >> 4) << 3;          // A/B-frag: k = (lane>>4)*8 + j
  f32x4 accP[8] = {{0.f, 0.f, 0.f, 0.f}};
  f32x4 accQ[8] = {{0.f, 0.f, 0.f, 0.f}};
#pragma unroll
  for (int nb = 1; nb < 8; nb++) { accP[nb] = accP[0]; accQ[nb] = accQ[0]; }
  const bf16x8* fsh = (const bf16x8*)FSh;
  const bf16x8* fsl = (const bf16x8*)FSl;
  const bf16x8* fdh = (const bf16x8*)FDh;
  const bf16x8* fdl = (const bf16x8*)FDl;
#pragma unroll
  for (int ks = 0; ks < 4; ks++) {
    bf16x8 ahi, alo;
    if (arow < M) {
      const float* ap = A + (size_t)arow * 128 + ks * 32 + koff;
      float4 v0 = *(const float4*)ap;
      float4 v1 = *(const float4*)(ap + 4);
      float va[8] = {v0.x, v0.y, v0.z, v0.w, v1.x, v1.y, v1.z, v1.w};
#pragma unroll
      for (int j = 0; j < 8; j++) {
        unsigned short h = f32_to_bf16_rne(va[j]);
        ahi[j] = (short)h;
        alo[j] = (short)f32_to_bf16_rne(va[j] - bf16_bits_to_f32(h));
      }
    } else {
#pragma unroll
      for (int j = 0; j < 8; j++) { ahi[j] = 0; alo[j] = 0; }
    }
#pragma unroll
    for (int nb = 0; nb < 8; nb++) {
      int fi = (ks * 8 + nb) * 64 + l;
      bf16x8 bsh = fsh[fi];
      bf16x8 bsl = fsl[fi];
      bf16x8 bdh = fdh[fi];
      bf16x8 bdl = fdl[fi];
      accP[nb] = __builtin_amdgcn_mfma_f32_16x16x32_bf16(ahi, bsh, accP[nb], 0, 0, 0);
      accP[nb] = __builtin_amdgcn_mfma_f32_16x16x32_bf16(alo, bsh, accP[nb], 0, 0, 0);
      accP[nb] = __builtin_amdgcn_mfma_f32_16x16x32_bf16(ahi, bsl, accP[nb], 0, 0, 0);
      accQ[nb] = __builtin_amdgcn_mfma_f32_16x16x32_bf16(ahi, bdh, accQ[nb], 0, 0, 0);
      accQ[nb] = __builtin_amdgcn_mfma_f32_16x16x32_bf16(alo, bdh, accQ[nb], 0, 0, 0);
      accQ[nb] = __builtin_amdgcn_mfma_f32_16x16x32_bf16(ahi, bdl, accQ[nb], 0, 0, 0);
    }
  }
  // D-frag: col = lane&15, row = (lane>>4)*4 + reg   [m89-verified mapping]
  const int rbase = r0 + ((l >> 4) << 2);
  const int cl = l & 15;
#pragma unroll
  for (int nb = 0; nb < 8; nb++) {
    int col = nb * 16 + cl;
    float bP = bs_[col], bQ = bd_[col];
#pragma unroll
    for (int r = 0; r < 4; r++) {
      int grow = rbase + r;
      if (grow < M) {
        P[(size_t)grow * 128 + col] = f32_to_bf16_rne(accP[nb][r] + bP);
        Q[(size_t)grow * 128 + col] = f32_to_bf16_rne(accQ[nb][r] + bQ);
      }
    }
  }
}

// ---------------- GATv2 aggregation ----------------
// One wave per dst node, 4 edges per wave-step.
// lane = (es = lane>>4: edge slot 0..3, ls = lane&15: dim-lane).
// Lane owns dims ls*8..ls*8+7 (head = ls>>2) of its slot's edge: one dwordx4
// gather covers a full 256B feature row per slot (4 edges per VMEM instr).
// Per-slot online softmax (m init -1e30; invalid edges t=-2e30 -> ex=0, sc=1),
// flash-merged across slots at the end via xor-16/32 butterfly.
__global__ __launch_bounds__(256, 4) void gat_agg_kernel(
    const unsigned short* __restrict__ P,  // fs bf16 [N,128]
    const unsigned short* __restrict__ Q,  // fd bf16 [N,128]
    const float* __restrict__ attn,        // [128] = [H=4][D=32]
    const int* __restrict__ row_start,
    const int* __restrict__ src_sorted,
    float* __restrict__ out, int N, int do_relu) {
  int wave = (int)((blockIdx.x * blockDim.x + threadIdx.x) >> 6);
  int lane = (int)(threadIdx.x & 63);
  if (wave >= N) return;
  const int es = lane >> 4;
  const int ls = lane & 15;

  float fd[8], av[8];
  decode8(*(const uint4*)&Q[(size_t)wave * 128 + ls * 8], fd);
  {
    float4 A0 = *(const float4*)&attn[ls * 8];
    float4 A1 = *(const float4*)&attn[ls * 8 + 4];
    av[0] = A0.x; av[1] = A0.y; av[2] = A0.z; av[3] = A0.w;
    av[4] = A1.x; av[5] = A1.y; av[6] = A1.z; av[7] = A1.w;
  }
  const int s0 = row_start[wave], s1 = row_start[wave + 1];

  float m = -1e30f, den = 0.f;
  float acc[8];
#pragma unroll
  for (int d = 0; d < 8; d++) acc[d] = 0.f;

  // pipeline prologue: idx+row of chunk 0, idx of chunk 1
  int i0 = s0 + es;
  int idx_c = (i0 < s1) ? src_sorted[i0] : 0;
  uint4 row_n = *(const uint4*)&P[(size_t)idx_c * 128 + ls * 8];
  int i1 = i0 + 4;
  int idx_n = (i1 < s1) ? src_sorted[i1] : 0;

#pragma unroll 1
  for (int base = s0; base < s1; base += 4) {
    uint4 row = row_n;
    // issue row gather for chunk c+1 (idx already resolved)
    row_n = *(const uint4*)&P[(size_t)idx_n * 128 + ls * 8];
    // load idx for chunk c+2
    int i2 = base + 8 + es;
    idx_n = (i2 < s1) ? src_sorted[i2] : 0;
    // compute chunk c
    float c[8];
    decode8(row, c);
    float t = 0.f;
#pragma unroll
    for (int d = 0; d < 8; d++) {
      float x = c[d] + fd[d];
      x = fmaxf(x, NEG_SLOPE * x);          // exact leaky_relu for slope<1
      t = fmaf(x, av[d], t);
    }
    t += __shfl_xor(t, 1);                  // reduce over the head's 4 lanes
    t += __shfl_xor(t, 2);
    t = (base + es < s1) ? t : -2e30f;      // invalid slot -> ex=0, sc=1
    float mn = fmaxf(m, t);
    float sc = __expf(m - mn);
    float ex = __expf(t - mn);
    den = den * sc + ex;
#pragma unroll
    for (int d = 0; d < 8; d++) acc[d] = fmaf(acc[d], sc, ex * c[d]);
    m = mn;
  }

  // flash-merge the 4 slots (lanes differing in bits 4,5 share ls -> same dims/head)
  float M2 = m;
  M2 = fmaxf(M2, __shfl_xor(M2, 16));
  M2 = fmaxf(M2, __shfl_xor(M2, 32));
  float sc = __expf(m - M2);                // empty slot: exp(-1e30-M2)=0 (M2 finite)
  den *= sc;
#pragma unroll
  for (int d = 0; d < 8; d++) acc[d] *= sc;
  den += __shfl_xor(den, 16);
  den += __shfl_xor(den, 32);
#pragma unroll
  for (int d = 0; d < 8; d++) {
    acc[d] += __shfl_xor(acc[d], 16);
    acc[d] += __shfl_xor(acc[d], 32);
  }

  if (es == 0) {
    float invd = (s1 > s0) ? 1.f / den : 0.f;
    float o[8];
#pragma unroll
    for (int d = 0; d < 8; d++) {
      o[d] = acc[d] * invd;
      if (do_relu) o[d] = fmaxf(o[d], 0.f);
    }
    float* op = out + (size_t)wave * 128 + ls * 8;
    *(float4*)op = make_float4(o[0], o[1], o[2], o[3]);
    *(float4*)(op + 4) = make_float4(o[4], o[5], o[6], o[7]);
  }
}

// ---------------- link-prediction scores: one wave per query ----------------
__global__ __launch_bounds__(256) void edge_score_kernel(
    const float* __restrict__ H, const int* __restrict__ qs, const int* __restrict__ qd,
    float* __restrict__ out, int NQ) {
  int wave = (int)((blockIdx.x * blockDim.x + threadIdx.x) >> 6);
  int lane = (int)(threadIdx.x & 63);
  if (wave >= NQ) return;
  int a = qs[wave], b = qd[wave];
  float2 x = *(const float2*)&H[(size_t)a * 128 + lane * 2];
  float2 y = *(const float2*)&H[(size_t)b * 128 + lane * 2];
  float t = x.x * y.x + x.y * y.y;
#pragma unroll
  for (int mask = 1; mask < 64; mask <<= 1) t += __shfl_xor(t, mask, 64);
  if (lane == 0) out[wave] = 1.f / (1.f + __expf(-t));
}

// ---------------- launch ----------------
extern "C" void kernel_launch(void* const* d_in, const int* in_sizes, int n_in,
                              void* d_out, int out_size, void* d_ws, size_t ws_size,
                              hipStream_t stream) {
  const float* feat  = (const float*)d_in[0];
  const int*   esrc  = (const int*)d_in[1];
  const int*   edst  = (const int*)d_in[2];
  const int*   qsrc  = (const int*)d_in[3];
  const int*   qdst  = (const int*)d_in[4];
  const float* W1s   = (const float*)d_in[5];
  const float* b1s   = (const float*)d_in[6];
  const float* W1d   = (const float*)d_in[7];
  const float* b1d   = (const float*)d_in[8];
  const float* attn1 = (const float*)d_in[9];
  const float* W2s   = (const float*)d_in[10];
  const float* b2s   = (const float*)d_in[11];
  const float* W2d   = (const float*)d_in[12];
  const float* b2d   = (const float*)d_in[13];
  const float* attn2 = (const float*)d_in[14];
  float* out = (float*)d_out;

  const int N  = in_sizes[0] / 128;
  const int E  = in_sizes[1];
  const int NQ = in_sizes[3];

  char* p = (char*)d_ws;
  auto alloc = [&](size_t bytes) -> char* {
    char* r = p;
    p += (bytes + 255) & ~(size_t)255;
    return r;
  };
  unsigned short* P = (unsigned short*)alloc((size_t)N * 128 * 2);  // bf16
  unsigned short* Q = (unsigned short*)alloc((size_t)N * 128 * 2);  // bf16
  float* H          = (float*)alloc((size_t)N * 128 * 4);
  int*   cnt        = (int*)alloc((size_t)N * 4);
  int*   row_start  = (int*)alloc((size_t)(N + 1) * 4);
  int*   cursor     = (int*)alloc((size_t)N * 4);
  int*   src_sorted = (int*)alloc((size_t)E * 4);
  int*   blk        = (int*)alloc(1024 * 4);
  unsigned short* FBhi = (unsigned short*)alloc(4 * 2048 * 8 * 2);  // 128KB
  unsigned short* FBlo = (unsigned short*)alloc(4 * 2048 * 8 * 2);

  // weight fragment pre-pack (independent of graph build)
  wfrag_kernel<<<32, 256, 0, stream>>>(W1s, W1d, W2s, W2d, FBhi, FBlo);

  // CSR build (edges grouped by dst; order within a node is arbitrary — sums only)
  const int nb = (N + 1023) / 1024;
  hipMemsetAsync(cnt, 0, (size_t)N * 4, stream);
  hist_kernel<<<(E + 255) / 256, 256, 0, stream>>>(edst, cnt, E);
  scan_block_kernel<<<nb, 1024, 0, stream>>>(cnt, row_start, blk, N);
  scan_tops_kernel<<<1, 1024, 0, stream>>>(blk, nb);
  scan_fixup_kernel<<<(N + 255) / 256, 256, 0, stream>>>(row_start, cursor, blk, N, E);
  scatter_kernel<<<(E + 255) / 256, 256, 0, stream>>>(edst, esrc, cursor, src_sorted, E);

  const int gblocks = (N + 63) / 64;
  const int per_mat = 2048 * 8;  // ushorts per matrix in FB buffers

  // layer 1
  gemm_mfma_dual<<<gblocks, 256, 0, stream>>>(
      feat, FBhi + 0 * per_mat, FBlo + 0 * per_mat, FBhi + 1 * per_mat, FBlo + 1 * per_mat,
      b1s, b1d, P, Q, N);
  gat_agg_kernel<<<(N + 3) / 4, 256, 0, stream>>>(P, Q, attn1, row_start, src_sorted, H, N, 1);

  // layer 2
  gemm_mfma_dual<<<gblocks, 256, 0, stream>>>(
      H, FBhi + 2 * per_mat, FBlo + 2 * per_mat, FBhi + 3 * per_mat, FBlo + 3 * per_mat,
      b2s, b2d, P, Q, N);
  gat_agg_kernel<<<(N + 3) / 4, 256, 0, stream>>>(P, Q, attn2, row_start, src_sorted, H, N, 0);

  // scores
  edge_score_kernel<<<(NQ + 3) / 4, 256, 0, stream>>>(H, qsrc, qdst, out, NQ);
}